// Round 1
// baseline (454.968 us; speedup 1.0000x reference)
//
#include <hip/hip_runtime.h>
#include <math.h>

#define Bn 32
#define An 8732
#define Cn 201
#define Gn 50

// ---------- helpers ----------
__device__ __forceinline__ unsigned int f2key(float f) {
    unsigned int u = __float_as_uint(f);
    return (u & 0x80000000u) ? ~u : (u | 0x80000000u);
}
__device__ __forceinline__ float key2f(unsigned int k) {
    return (k & 0x80000000u) ? __uint_as_float(k & 0x7FFFFFFFu) : __uint_as_float(~k);
}
__device__ __forceinline__ float smooth_l1(float d) {
    float ad = fabsf(d);
    return ad < 1.0f ? 0.5f * d * d : ad - 0.5f;
}

// ---------- kernel 0: zero the accumulators (ws is re-poisoned each call) ----------
__global__ void init_kernel(int* fg_count, float* fg_cls_sum, float* bbox_sum) {
    int i = threadIdx.x;
    if (i < Bn) fg_count[i] = 0;
    if (i == 0) { *fg_cls_sum = 0.f; *bbox_sum = 0.f; }
}

// ---------- kernel 1: per-anchor CE (one wave per anchor) + fg bbox loss ----------
__global__ __launch_bounds__(256) void cls_kernel(
        const float* __restrict__ cls_logits,      // [B,A,C]
        const int*   __restrict__ matched_idxs,    // [B,A]
        const int*   __restrict__ labels,          // [B,G]
        const float* __restrict__ boxes,           // [B,G,4]
        const float* __restrict__ anchors,         // [B,A,4]
        const float* __restrict__ bbox_regression, // [B,A,4]
        float* __restrict__ neg_loss,              // [B,A] out
        int*   __restrict__ fg_count,              // [B]
        float* __restrict__ fg_cls_sum,
        float* __restrict__ bbox_sum) {
    int wave = (blockIdx.x * blockDim.x + threadIdx.x) >> 6;
    int lane = threadIdx.x & 63;
    if (wave >= Bn * An) return;
    int b = wave / An;

    const float* lg = cls_logits + (size_t)wave * Cn;
    // 201 logits over 64 lanes: lane, lane+64, lane+128, (+192 for lane<9)
    float v0 = lg[lane];
    float v1 = lg[lane + 64];
    float v2 = lg[lane + 128];
    bool  has3 = (lane < Cn - 192);
    float v3 = has3 ? lg[lane + 192] : -INFINITY;

    float mx = fmaxf(fmaxf(v0, v1), fmaxf(v2, v3));
    #pragma unroll
    for (int off = 32; off; off >>= 1) mx = fmaxf(mx, __shfl_xor(mx, off, 64));

    float s = expf(v0 - mx) + expf(v1 - mx) + expf(v2 - mx)
            + (has3 ? expf(v3 - mx) : 0.f);
    #pragma unroll
    for (int off = 32; off; off >>= 1) s += __shfl_xor(s, off, 64);

    if (lane == 0) {
        float lse = mx + logf(s);
        int   mi  = matched_idxs[wave];
        bool  fg  = (mi >= 0);
        int   t   = fg ? labels[b * Gn + mi] : 0;
        float cl  = lse - lg[t];
        if (fg) {
            neg_loss[wave] = -INFINITY;
            atomicAdd(fg_cls_sum, cl);
            atomicAdd(&fg_count[b], 1);
            // bbox smooth-L1 vs encoded target (torchvision BoxCoder, w=10,10,5,5)
            const float* gt = boxes           + (size_t)(b * Gn + mi) * 4;
            const float* an = anchors         + (size_t)wave * 4;
            const float* rg = bbox_regression + (size_t)wave * 4;
            float aw  = an[2] - an[0], ah  = an[3] - an[1];
            float acx = an[0] + 0.5f * aw, acy = an[1] + 0.5f * ah;
            float gw  = gt[2] - gt[0], gh  = gt[3] - gt[1];
            float gcx = gt[0] + 0.5f * gw, gcy = gt[1] + 0.5f * gh;
            float t0 = 10.f * (gcx - acx) / aw;
            float t1 = 10.f * (gcy - acy) / ah;
            float t2 = 5.f * logf(gw / aw);
            float t3 = 5.f * logf(gh / ah);
            float sum = smooth_l1(rg[0] - t0) + smooth_l1(rg[1] - t1)
                      + smooth_l1(rg[2] - t2) + smooth_l1(rg[3] - t3);
            atomicAdd(bbox_sum, sum);
        } else {
            neg_loss[wave] = cl;
        }
    }
}

// ---------- kernel 2: per-batch top-k sum via 4-pass byte radix select ----------
__global__ __launch_bounds__(256) void mining_kernel(
        const float* __restrict__ neg_loss,   // [B,A]
        const int*   __restrict__ fg_count,   // [B]
        float* __restrict__ topk_batch) {     // [B] out
    int b = blockIdx.x;
    __shared__ unsigned int hist[256];
    __shared__ unsigned int sh_prefix;
    __shared__ int sh_remaining;
    __shared__ float sh_sum;
    __shared__ int sh_cnt;

    int fc = fg_count[b];
    int k = 3 * fc;
    int nneg = An - fc;
    if (k > nneg) k = nneg;   // fg entries key below all real losses; unreachable at 2% fg
    if (k <= 0) {
        if (threadIdx.x == 0) topk_batch[b] = 0.f;
        return;
    }
    const float* vals = neg_loss + (size_t)b * An;

    if (threadIdx.x == 0) { sh_prefix = 0u; sh_remaining = k; }
    for (int byte = 3; byte >= 0; --byte) {
        for (int i = threadIdx.x; i < 256; i += blockDim.x) hist[i] = 0u;
        __syncthreads();
        unsigned int prefix = sh_prefix;
        unsigned int himask = (byte == 3) ? 0u : (0xFFFFFFFFu << ((byte + 1) * 8));
        for (int i = threadIdx.x; i < An; i += blockDim.x) {
            unsigned int key = f2key(vals[i]);
            if ((key & himask) == prefix)
                atomicAdd(&hist[(key >> (byte * 8)) & 255u], 1u);
        }
        __syncthreads();
        if (threadIdx.x == 0) {
            int rem = sh_remaining;
            unsigned int cum = 0;
            int bin = 255;
            for (; bin > 0; --bin) {
                cum += hist[bin];
                if ((int)cum >= rem) break;
            }
            if (bin == 0) cum += hist[0];
            rem -= (int)(cum - hist[bin]);
            sh_remaining = rem;
            sh_prefix = prefix | ((unsigned int)bin << (byte * 8));
        }
        __syncthreads();
    }
    unsigned int kth = sh_prefix;   // exact key of the k-th largest element

    float lsum = 0.f; int lcnt = 0;
    for (int i = threadIdx.x; i < An; i += blockDim.x) {
        unsigned int key = f2key(vals[i]);
        if (key > kth) { lsum += key2f(key); lcnt++; }
    }
    if (threadIdx.x == 0) { sh_sum = 0.f; sh_cnt = 0; }
    __syncthreads();
    atomicAdd(&sh_sum, lsum);
    atomicAdd(&sh_cnt, lcnt);
    __syncthreads();
    if (threadIdx.x == 0) {
        // ties at the threshold contribute identical values -> exact sum
        topk_batch[b] = sh_sum + (float)(k - sh_cnt) * key2f(kth);
    }
}

// ---------- kernel 3: finalize (one wave) ----------
__global__ void finalize_kernel(
        const int*   __restrict__ fg_count,
        const float* __restrict__ fg_cls_sum,
        const float* __restrict__ bbox_sum,
        const float* __restrict__ topk_batch,
        const float* __restrict__ rejection_logits,  // [B,2]
        const int*   __restrict__ image_label,       // [B]
        float* __restrict__ out) {
    int lane = threadIdx.x;
    int   fc = (lane < Bn) ? fg_count[lane] : 0;
    float tk = (lane < Bn) ? topk_batch[lane] : 0.f;
    float vl = 0.f;
    if (lane < Bn) {
        float r0 = rejection_logits[lane * 2];
        float r1 = rejection_logits[lane * 2 + 1];
        float m  = fmaxf(r0, r1);
        float lse = m + logf(expf(r0 - m) + expf(r1 - m));
        vl = lse - ((image_label[lane] == 0) ? r0 : r1);
    }
    #pragma unroll
    for (int off = 32; off; off >>= 1) {
        fc += __shfl_xor(fc, off, 64);
        tk += __shfl_xor(tk, off, 64);
        vl += __shfl_xor(vl, off, 64);
    }
    if (lane == 0) {
        float N   = (float)((fc > 1) ? fc : 1);
        float reg = bbox_sum[0] / N;
        float cls = (fg_cls_sum[0] + tk) / N;   // N_neg = 0 (MIN_NEG_SAMPLES = 0)
        float val = vl / (float)Bn;
        float loss = 0.5f * (reg + cls) + 0.5f * val;
        out[0] = loss; out[1] = reg; out[2] = cls; out[3] = val;
    }
}

extern "C" void kernel_launch(void* const* d_in, const int* in_sizes, int n_in,
                              void* d_out, int out_size, void* d_ws, size_t ws_size,
                              hipStream_t stream) {
    const float* boxes            = (const float*)d_in[0];
    const int*   labels           = (const int*)  d_in[1];
    const int*   image_label      = (const int*)  d_in[2];
    const float* bbox_regression  = (const float*)d_in[3];
    const float* cls_logits       = (const float*)d_in[4];
    const float* rejection_logits = (const float*)d_in[5];
    const float* anchors          = (const float*)d_in[6];
    const int*   matched_idxs     = (const int*)  d_in[7];
    float* out = (float*)d_out;

    // workspace layout
    float* neg_loss   = (float*)d_ws;                 // B*A floats
    int*   fg_count   = (int*)(neg_loss + Bn * An);   // B ints
    float* fg_cls_sum = (float*)(fg_count + Bn);      // 1
    float* bbox_sum   = fg_cls_sum + 1;               // 1
    float* topk_batch = bbox_sum + 1;                 // B

    init_kernel<<<1, 64, 0, stream>>>(fg_count, fg_cls_sum, bbox_sum);

    int waves  = Bn * An;                 // one wave per anchor
    int blocks = (waves * 64 + 255) / 256;
    cls_kernel<<<blocks, 256, 0, stream>>>(cls_logits, matched_idxs, labels,
                                           boxes, anchors, bbox_regression,
                                           neg_loss, fg_count, fg_cls_sum, bbox_sum);

    mining_kernel<<<Bn, 256, 0, stream>>>(neg_loss, fg_count, topk_batch);

    finalize_kernel<<<1, 64, 0, stream>>>(fg_count, fg_cls_sum, bbox_sum, topk_batch,
                                          rejection_logits, image_label, out);
}

// Round 2
// 349.828 us; speedup vs baseline: 1.3005x; 1.3005x over previous
//
#include <hip/hip_runtime.h>
#include <math.h>

#define Bn 32
#define An 8732
#define Cn 201
#define Gn 50

#define APB 16                      // anchors per block in cls kernel (16 lanes/anchor, 256 thr)
#define CLS_BLOCKS ((An + APB - 1) / APB)   // 546 blocks per batch

// ---------- helpers ----------
__device__ __forceinline__ unsigned int f2key(float f) {
    unsigned int u = __float_as_uint(f);
    return (u & 0x80000000u) ? ~u : (u | 0x80000000u);
}
__device__ __forceinline__ float key2f(unsigned int k) {
    return (k & 0x80000000u) ? __uint_as_float(k & 0x7FFFFFFFu) : __uint_as_float(~k);
}
__device__ __forceinline__ float smooth_l1(float d) {
    float ad = fabsf(d);
    return ad < 1.0f ? 0.5f * d * d : ad - 0.5f;
}

// ---------- kernel 0: zero per-batch accumulators (ws re-poisoned each call) ----------
__global__ void init_kernel(int* fg_count, float* fg_cls_sum, float* bbox_sum) {
    int i = threadIdx.x;
    if (i < Bn) { fg_count[i] = 0; fg_cls_sum[i] = 0.f; bbox_sum[i] = 0.f; }
}

// ---------- kernel 1: per-anchor CE, 16 lanes per anchor ----------
__global__ __launch_bounds__(256) void cls_kernel(
        const float* __restrict__ cls_logits,      // [B,A,C]
        const int*   __restrict__ matched_idxs,    // [B,A]
        const int*   __restrict__ labels,          // [B,G]
        const float* __restrict__ boxes,           // [B,G,4]
        const float* __restrict__ anchors,         // [B,A,4]
        const float* __restrict__ bbox_regression, // [B,A,4]
        float* __restrict__ neg_loss,              // [B,A] out
        int*   __restrict__ fg_count,              // [B]
        float* __restrict__ fg_cls_sum,            // [B]
        float* __restrict__ bbox_sum) {            // [B]
    int b   = blockIdx.y;
    int a   = blockIdx.x * APB + (threadIdx.x >> 4);   // anchor within batch
    int sub = threadIdx.x & 15;                        // lane within anchor group
    if (a >= An) return;
    size_t row_idx = (size_t)b * An + a;
    const float* lg = cls_logits + row_idx * Cn;

    // 201 elements over 16 lanes: sub + 16j, j = 0..12 (j=12 only for sub<9)
    float v[13];
    #pragma unroll
    for (int j = 0; j < 12; ++j) v[j] = lg[sub + 16 * j];
    bool has12 = (sub < Cn - 192);
    v[12] = has12 ? lg[sub + 192] : -INFINITY;

    float mx = v[0];
    #pragma unroll
    for (int j = 1; j < 13; ++j) mx = fmaxf(mx, v[j]);
    #pragma unroll
    for (int off = 8; off; off >>= 1) mx = fmaxf(mx, __shfl_xor(mx, off, 64));

    float s = 0.f;
    #pragma unroll
    for (int j = 0; j < 12; ++j) s += expf(v[j] - mx);
    if (has12) s += expf(v[12] - mx);
    #pragma unroll
    for (int off = 8; off; off >>= 1) s += __shfl_xor(s, off, 64);

    if (sub == 0) {
        float lse = mx + logf(s);
        int   mi  = matched_idxs[row_idx];
        bool  fg  = (mi >= 0);
        int   t   = fg ? labels[b * Gn + mi] : 0;
        float cl  = lse - lg[t];
        if (fg) {
            neg_loss[row_idx] = -INFINITY;
            atomicAdd(&fg_cls_sum[b], cl);
            atomicAdd(&fg_count[b], 1);
            const float* gt = boxes           + (size_t)(b * Gn + mi) * 4;
            const float* an = anchors         + row_idx * 4;
            const float* rg = bbox_regression + row_idx * 4;
            float aw  = an[2] - an[0], ah  = an[3] - an[1];
            float acx = an[0] + 0.5f * aw, acy = an[1] + 0.5f * ah;
            float gw  = gt[2] - gt[0], gh  = gt[3] - gt[1];
            float gcx = gt[0] + 0.5f * gw, gcy = gt[1] + 0.5f * gh;
            float t0 = 10.f * (gcx - acx) / aw;
            float t1 = 10.f * (gcy - acy) / ah;
            float t2 = 5.f * logf(gw / aw);
            float t3 = 5.f * logf(gh / ah);
            float sum = smooth_l1(rg[0] - t0) + smooth_l1(rg[1] - t1)
                      + smooth_l1(rg[2] - t2) + smooth_l1(rg[3] - t3);
            atomicAdd(&bbox_sum[b], sum);
        } else {
            neg_loss[row_idx] = cl;
        }
    }
}

// ---------- kernel 2: per-batch top-k sum via register-resident bit binary search ----------
#define MIT 9   // ceil(8732 / 1024) elements per thread
__global__ __launch_bounds__(1024) void mining_kernel(
        const float* __restrict__ neg_loss,   // [B,A]
        const int*   __restrict__ fg_count,   // [B]
        float* __restrict__ topk_batch) {     // [B] out
    int b    = blockIdx.x;
    int tid  = threadIdx.x;
    int lane = tid & 63;
    __shared__ int   cnts[32];
    __shared__ float sh_sum;
    __shared__ int   sh_cnt;

    int fc = fg_count[b];
    int k  = 3 * fc;
    int nneg = An - fc;
    if (k > nneg) k = nneg;
    if (k <= 0) {
        if (tid == 0) topk_batch[b] = 0.f;
        return;
    }

    // load this thread's elements once; convert to order-preserving uint keys.
    // pads and fg(-inf) keys are < f2key(0.0)=0x80000000 <= any real CE loss,
    // and k <= #negatives guarantees the k-th largest is a real loss.
    const float* vals = neg_loss + (size_t)b * An;
    unsigned int key[MIT];
    #pragma unroll
    for (int j = 0; j < MIT; ++j) {
        int i = tid + j * 1024;
        key[j] = (i < An) ? f2key(vals[i]) : 0u;
    }

    if (tid < 32) cnts[tid] = 0;
    if (tid == 0) { sh_sum = 0.f; sh_cnt = 0; }
    __syncthreads();

    // T = max{t : count(key >= t) >= k}  ==  k-th largest key (MSB-first greedy)
    unsigned int T = 0u;
    for (int bit = 31; bit >= 0; --bit) {
        unsigned int cand = T | (1u << bit);
        int c = 0;
        #pragma unroll
        for (int j = 0; j < MIT; ++j) c += (key[j] >= cand);
        #pragma unroll
        for (int off = 32; off; off >>= 1) c += __shfl_xor(c, off, 64);
        if (lane == 0) atomicAdd(&cnts[bit], c);
        __syncthreads();
        if (cnts[bit] >= k) T = cand;
    }

    // exact sum: strictly-greater elements + tie correction at the threshold
    float fs = 0.f; int cgt = 0;
    #pragma unroll
    for (int j = 0; j < MIT; ++j)
        if (key[j] > T) { fs += key2f(key[j]); cgt++; }
    #pragma unroll
    for (int off = 32; off; off >>= 1) {
        fs  += __shfl_xor(fs,  off, 64);
        cgt += __shfl_xor(cgt, off, 64);
    }
    if (lane == 0) { atomicAdd(&sh_sum, fs); atomicAdd(&sh_cnt, cgt); }
    __syncthreads();
    if (tid == 0)
        topk_batch[b] = sh_sum + (float)(k - sh_cnt) * key2f(T);
}

// ---------- kernel 3: finalize (one wave) ----------
__global__ void finalize_kernel(
        const int*   __restrict__ fg_count,
        const float* __restrict__ fg_cls_sum,
        const float* __restrict__ bbox_sum,
        const float* __restrict__ topk_batch,
        const float* __restrict__ rejection_logits,  // [B,2]
        const int*   __restrict__ image_label,       // [B]
        float* __restrict__ out) {
    int lane = threadIdx.x;
    int   fc = (lane < Bn) ? fg_count[lane]   : 0;
    float tk = (lane < Bn) ? topk_batch[lane] : 0.f;
    float cs = (lane < Bn) ? fg_cls_sum[lane] : 0.f;
    float bs = (lane < Bn) ? bbox_sum[lane]   : 0.f;
    float vl = 0.f;
    if (lane < Bn) {
        float r0 = rejection_logits[lane * 2];
        float r1 = rejection_logits[lane * 2 + 1];
        float m  = fmaxf(r0, r1);
        float lse = m + logf(expf(r0 - m) + expf(r1 - m));
        vl = lse - ((image_label[lane] == 0) ? r0 : r1);
    }
    #pragma unroll
    for (int off = 32; off; off >>= 1) {
        fc += __shfl_xor(fc, off, 64);
        tk += __shfl_xor(tk, off, 64);
        cs += __shfl_xor(cs, off, 64);
        bs += __shfl_xor(bs, off, 64);
        vl += __shfl_xor(vl, off, 64);
    }
    if (lane == 0) {
        float N   = (float)((fc > 1) ? fc : 1);
        float reg = bs / N;
        float cls = (cs + tk) / N;   // N_neg = 0 (MIN_NEG_SAMPLES = 0)
        float val = vl / (float)Bn;
        float loss = 0.5f * (reg + cls) + 0.5f * val;
        out[0] = loss; out[1] = reg; out[2] = cls; out[3] = val;
    }
}

extern "C" void kernel_launch(void* const* d_in, const int* in_sizes, int n_in,
                              void* d_out, int out_size, void* d_ws, size_t ws_size,
                              hipStream_t stream) {
    const float* boxes            = (const float*)d_in[0];
    const int*   labels           = (const int*)  d_in[1];
    const int*   image_label      = (const int*)  d_in[2];
    const float* bbox_regression  = (const float*)d_in[3];
    const float* cls_logits       = (const float*)d_in[4];
    const float* rejection_logits = (const float*)d_in[5];
    const float* anchors          = (const float*)d_in[6];
    const int*   matched_idxs     = (const int*)  d_in[7];
    float* out = (float*)d_out;

    // workspace layout
    float* neg_loss   = (float*)d_ws;                 // B*A floats
    int*   fg_count   = (int*)(neg_loss + Bn * An);   // B
    float* fg_cls_sum = (float*)(fg_count + Bn);      // B
    float* bbox_sum   = fg_cls_sum + Bn;              // B
    float* topk_batch = bbox_sum + Bn;                // B

    init_kernel<<<1, 64, 0, stream>>>(fg_count, fg_cls_sum, bbox_sum);

    dim3 grid(CLS_BLOCKS, Bn);
    cls_kernel<<<grid, 256, 0, stream>>>(cls_logits, matched_idxs, labels,
                                         boxes, anchors, bbox_regression,
                                         neg_loss, fg_count, fg_cls_sum, bbox_sum);

    mining_kernel<<<Bn, 1024, 0, stream>>>(neg_loss, fg_count, topk_batch);

    finalize_kernel<<<1, 64, 0, stream>>>(fg_count, fg_cls_sum, bbox_sum, topk_batch,
                                          rejection_logits, image_label, out);
}